// Round 5
// baseline (616.536 us; speedup 1.0000x reference)
//
#include <hip/hip_runtime.h>

// Problem constants
#define NROWS 8192
#define DDIM  512
#define MEXP  2048
#define BDIM  4
#define KTOP  8
#define EBLK  512          // energy kernel blocks (16 rows each, contiguous)
#define SLICES 16          // second-stage reduce slices (512/32)

typedef unsigned long long ull;

// d_out layout (floats): h_sparse [0,262144), idx [262144,327680), 7 scalars at 327680
#define OUT_IDX     262144
#define OUT_SCAL    327680

// d_ws layout (bytes) — no global atomics; all partials plain-stored
#define WS_VT_OFF    0u                       // 16 MiB: Vt[m][d] float4 (b-dim)
#define WS_ESP_OFF   16777216u                // 512*2048 f32 = 4 MiB
#define WS_CNTP_OFF  20971520u                // 512*2048 u32 = 4 MiB
#define WS_CAP_OFF   25165824u                // 512 f32
#define WS_LRLH_OFF  25167872u                // 8192 float2 = 64 KiB
#define WS_ES2_OFF   25233408u                // 16*2048 f32 = 128 KiB
#define WS_CNT2_OFF  25364480u                // 16*2048 u32 = 128 KiB

typedef __attribute__((address_space(1))) unsigned int gu32;
typedef __attribute__((address_space(3))) unsigned int lu32;

// descending compare-exchange (keep a >= b)
#define CE(a, b) do { const ull _mx = ((a) > (b)) ? (a) : (b); \
                      const ull _mn = ((a) > (b)) ? (b) : (a); \
                      (a) = _mx; (b) = _mn; } while (0)

// ---------------------------------------------------------------------------
// Kernel 1: BLOCK-CONTIGUOUS streaming energy + top-8.
// Post-mortem rounds 0-4: three structurally different wave-per-row variants
// (LDS-DMA+drain, reg-serial, reg-dbuf; waves 1024->8192, in-flight 2->16KB)
// ALL converge at ~0.9 TB/s HBM / ~1.85 TB/s logical — the invariant is the
// access SHAPE (thousands of 1KB-granule streams at 32KB stride over 256 MiB),
// not TLP or per-wave depth. Fills/copy stream contiguously at 6.3-6.7 TB/s.
// Fix: one block owns 16 CONSECUTIVE rows = one contiguous 512 KB region,
// streamed as 8 x 64KB chunks via global_load_lds (linear LDS dest), 2-phase
// pipelined with counted vmcnt(4) — never drained to 0 mid-loop — and raw
// s_barrier (no __syncthreads: it would emit vmcnt(0) and kill the prefetch).
// Chunk = 2 rows; 8 waves per row each top-8 a 256-expert slice (sorted-4 per
// lane + 8-round argmax), then one wave merges 64 candidates per row.
// Winner set/order identical to full-row scan (same key = energy || ~index).
// capw per row in descending order == jnp.sum(topk_vals, axis=-1) order.
// ---------------------------------------------------------------------------
__global__ __launch_bounds__(1024, 4) void energy_topk_kernel(
    const float* __restrict__ h_all, float* __restrict__ out,
    float* __restrict__ esum_part, unsigned int* __restrict__ cnt_part,
    float* __restrict__ cap_part)
{
    __shared__ float4 stage[2][4096];     // 128 KB: 2 x 64KB chunks (2 rows each)
    __shared__ float s_es[MEXP];          // 8 KB
    __shared__ unsigned int s_cnt[MEXP];  // 8 KB
    __shared__ ull   s_merge[2][64];      // 1 KB: per-row 8 waves x 8 candidates
    __shared__ float s_capr[16];          // per-row captured sums

    const int t    = threadIdx.x;
    const int lane = t & 63;
    const int wid  = t >> 6;              // 0..15
    const int bid  = blockIdx.x;

    for (int j = t; j < MEXP; j += 1024) { s_es[j] = 0.f; s_cnt[j] = 0u; }

    // block's contiguous region: rows [bid*16, bid*16+16) = 512 KB
    const size_t gbase4 = (size_t)bid * (16 * MEXP);   // float4 units

    // issue chunk 0 (each thread 4 x 16B direct-to-LDS; LDS dest wave-uniform)
#define ISSUE(cc, bb)                                                         \
    do {                                                                      \
        _Pragma("unroll")                                                     \
        for (int i = 0; i < 4; ++i) {                                         \
            const size_t g4 = gbase4 + (size_t)(cc) * 4096 + i * 1024 +       \
                              wid * 64 + lane;                                \
            __builtin_amdgcn_global_load_lds(                                 \
                (gu32*)h_all + g4 * 4,                                        \
                (lu32*)((unsigned int*)&stage[bb][0] +                        \
                        (size_t)(i * 1024 + wid * 64) * 4),                   \
                16, 0, 0);                                                    \
        }                                                                     \
    } while (0)

    ISSUE(0, 0);
    int cur = 0;

    const int row = wid >> 3;             // 0/1: which row of the chunk
    const int s   = wid & 7;              // slice within row

    for (int c = 0; c < 8; ++c) {
        if (c < 7) {
            ISSUE(c + 1, cur ^ 1);
            // chunk c's 4 oldest loads retired; chunk c+1's 4 stay in flight.
            asm volatile("s_waitcnt vmcnt(4) lgkmcnt(0)" ::: "memory");
        } else {
            asm volatile("s_waitcnt vmcnt(0) lgkmcnt(0)" ::: "memory");
        }
        __builtin_amdgcn_s_barrier();     // A: chunk c visible to all waves

        // ---- stage 1: energy + per-lane sorted top-4 of this wave's slice
        const float4* rb = &stage[cur][row * 2048 + s * 256];
        ull kk[4];
#pragma unroll
        for (int j = 0; j < 4; ++j) {
            const int mloc = j * 64 + lane;
            const int m    = s * 256 + mloc;
            const float4 h = rb[mloc];    // ds_read_b128, conflict-free
            // bit-exact numpy f32 sequential sum (no FMA contraction)
            const float e = __fadd_rn(__fadd_rn(__fadd_rn(__fmul_rn(h.x, h.x),
                                                          __fmul_rn(h.y, h.y)),
                                                __fmul_rn(h.z, h.z)),
                                      __fmul_rn(h.w, h.w));
            atomicAdd(&s_es[m], e);       // ds_add_f32, distinct addr per lane
            kk[j] = ((ull)__float_as_uint(e) << 32) |
                    (ull)(0xFFFFFFFFu - (unsigned)m);
        }
        CE(kk[0], kk[1]); CE(kk[2], kk[3]);
        CE(kk[0], kk[2]); CE(kk[1], kk[3]); CE(kk[1], kk[2]);

        // ---- stage 2: wave-wide top-8 of the 256-slice (8 argmax rounds)
        ull myk = 0ull;
#pragma unroll
        for (int round = 0; round < 8; ++round) {
            ull w = kk[0];
#pragma unroll
            for (int off = 1; off < 64; off <<= 1) {
                const ull o = __shfl_xor(w, off, 64);
                w = (o > w) ? o : w;
            }
            if (lane == round) myk = w;
            const bool own = (kk[0] == w);       // keys unique
            kk[0] = own ? kk[1] : kk[0];
            kk[1] = own ? kk[2] : kk[1];
            kk[2] = own ? kk[3] : kk[2];
            kk[3] = own ? 0ull  : kk[3];
        }
        if (lane < 8) s_merge[row][s * 8 + lane] = myk;

        asm volatile("s_waitcnt lgkmcnt(0)" ::: "memory");
        __builtin_amdgcn_s_barrier();     // C: merge candidates visible

        // ---- stage 3: one wave per row merges 64 candidates -> global top-8
        if (s == 0) {                     // wid 0 (row 0) and wid 8 (row 1)
            ull cand = s_merge[row][lane];
            float capr = 0.f;
            int mym = 0;
#pragma unroll
            for (int round = 0; round < 8; ++round) {
                ull w = cand;
#pragma unroll
                for (int off = 1; off < 64; off <<= 1) {
                    const ull o = __shfl_xor(w, off, 64);
                    w = (o > w) ? o : w;
                }
                if (lane == round) mym = (int)(0xFFFFFFFFu -
                                               (unsigned)(w & 0xFFFFFFFFull));
                if (lane == 0) capr += __uint_as_float((unsigned)(w >> 32));
                if (cand == w) cand = 0ull;
            }
            const int n = bid * 16 + c * 2 + row;
            if (lane < KTOP) {
                const float4 hv = stage[cur][row * 2048 + mym];  // LDS gather
                ((float4*)out)[(size_t)n * KTOP + lane] = hv;    // h_sparse
                out[OUT_IDX + (size_t)n * KTOP + lane] = (float)mym;
                atomicAdd(&s_cnt[mym], 1u);
            }
            if (lane == 0) s_capr[c * 2 + row] = capr;           // desc order
        }

        asm volatile("s_waitcnt lgkmcnt(0)" ::: "memory");
        __builtin_amdgcn_s_barrier();     // B: all reads of stage[cur] done
        cur ^= 1;
    }
#undef ISSUE

    // flush per-block partials with plain coalesced stores
    float*        ep = esum_part + (size_t)bid * MEXP;
    unsigned int* cp = cnt_part  + (size_t)bid * MEXP;
    for (int j = t; j < MEXP; j += 1024) { ep[j] = s_es[j]; cp[j] = s_cnt[j]; }
    if (t == 0) {
        float ccap = 0.f;
#pragma unroll
        for (int r = 0; r < 16; ++r) ccap += s_capr[r];
        cap_part[bid] = ccap;
    }
}

// ---------------------------------------------------------------------------
// Kernel 2: transpose V (D,M,B) -> Vt (M,D,B), float4 elements over b
// ---------------------------------------------------------------------------
__global__ __launch_bounds__(256) void transpose_v_kernel(
    const float4* __restrict__ V, float4* __restrict__ Vt)
{
    __shared__ float4 tile[32][33];
    const int bx = blockIdx.x;       // m tile: 0..63
    const int by = blockIdx.y;       // d tile: 0..15
    const int tx = threadIdx.x & 31;
    const int ty = threadIdx.x >> 5; // 0..7

#pragma unroll
    for (int i = 0; i < 4; ++i) {
        const int d = by * 32 + ty + i * 8;
        const int m = bx * 32 + tx;
        tile[ty + i * 8][tx] = V[(size_t)d * MEXP + m];
    }
    __syncthreads();
#pragma unroll
    for (int i = 0; i < 4; ++i) {
        const int m = bx * 32 + ty + i * 8;
        const int d = by * 32 + tx;
        Vt[(size_t)m * DDIM + d] = tile[tx][ty + i * 8];
    }
}

// ---------------------------------------------------------------------------
// Kernel 3: x_hat per row; per-block (lr,lh) stored to ws — ZERO atomics
// ---------------------------------------------------------------------------
__global__ __launch_bounds__(256) void recon_kernel(
    const float* __restrict__ x_flat, const float* __restrict__ out_ro,
    const float4* __restrict__ Vt, float2* __restrict__ lrlh)
{
    __shared__ float4 s_h[KTOP];
    __shared__ int    s_m[KTOP];
    __shared__ float  s_lr[4], s_lh[4];

    const int n    = blockIdx.x;
    const int t    = threadIdx.x;
    const int lane = t & 63;
    const int wid  = t >> 6;

    if (t < KTOP) {
        s_m[t] = (int)out_ro[OUT_IDX + (size_t)n * KTOP + t];
        s_h[t] = ((const float4*)out_ro)[(size_t)n * KTOP + t];
    }
    __syncthreads();

    float4 v0[KTOP], v1[KTOP];
#pragma unroll
    for (int k = 0; k < KTOP; ++k) {
        const size_t o = (size_t)s_m[k] * DDIM;
        v0[k] = Vt[o + t];          // lanes -> consecutive float4: coalesced
        v1[k] = Vt[o + t + 256];
    }
    const float x0 = x_flat[(size_t)n * DDIM + t];
    const float x1 = x_flat[(size_t)n * DDIM + t + 256];

    float xh0 = 0.f, xh1 = 0.f;
#pragma unroll
    for (int k = 0; k < KTOP; ++k) {
        const float4 hv = s_h[k];
        xh0 += v0[k].x * hv.x + v0[k].y * hv.y + v0[k].z * hv.z + v0[k].w * hv.w;
        xh1 += v1[k].x * hv.x + v1[k].y * hv.y + v1[k].z * hv.z + v1[k].w * hv.w;
    }

    const float r0 = x0 - xh0, r1 = x1 - xh1;
    float lr = r0 * r0 + r1 * r1;
    float lh = xh0 * xh0 + xh1 * xh1;

#pragma unroll
    for (int off = 32; off > 0; off >>= 1) {
        lr += __shfl_down(lr, off, 64);
        lh += __shfl_down(lh, off, 64);
    }
    if (lane == 0) { s_lr[wid] = lr; s_lh[wid] = lh; }
    __syncthreads();
    if (t == 0) {
        lrlh[n] = make_float2(s_lr[0] + s_lr[1] + s_lr[2] + s_lr[3],
                              s_lh[0] + s_lh[1] + s_lh[2] + s_lh[3]);
    }
}

// ---------------------------------------------------------------------------
// Kernel 4: stage-1 reduce of per-block expert partials: 512 -> 16 slices.
// ---------------------------------------------------------------------------
__global__ __launch_bounds__(256) void reduce_expert_kernel(
    const float* __restrict__ esum_part, const unsigned int* __restrict__ cnt_part,
    float* __restrict__ es2, unsigned int* __restrict__ cnt2)
{
    const int e = blockIdx.x * 256 + threadIdx.x;   // 8 blocks -> 2048
    const int s = blockIdx.y;                       // 16 slices
    float sum = 0.f;
    unsigned int c = 0u;
#pragma unroll
    for (int b = 0; b < 32; ++b) {
        const size_t row = (size_t)(s * 32 + b);
        sum += esum_part[row * MEXP + e];           // coalesced across lanes
        c   += cnt_part [row * MEXP + e];
    }
    es2 [(size_t)s * MEXP + e] = sum;
    cnt2[(size_t)s * MEXP + e] = c;
}

// ---------------------------------------------------------------------------
// Kernel 5: finalize scalars
// ---------------------------------------------------------------------------
__device__ __forceinline__ double block_reduce_d(double v, double* s4,
                                                 int lane, int wid)
{
#pragma unroll
    for (int off = 32; off > 0; off >>= 1) v += __shfl_down(v, off, 64);
    if (lane == 0) s4[wid] = v;
    __syncthreads();
    const double r = s4[0] + s4[1] + s4[2] + s4[3];
    __syncthreads();
    return r;
}

__global__ __launch_bounds__(256) void finalize_kernel(
    const float* __restrict__ es2, const unsigned int* __restrict__ cnt2,
    const float* __restrict__ cap_part, const float2* __restrict__ lrlh,
    float* __restrict__ out)
{
    __shared__ double s4[4];
    const int t = threadIdx.x, lane = t & 63, wid = t >> 6;

    double avg[8];
    unsigned int cnt[8];
    double tot = 0.0;
#pragma unroll
    for (int j = 0; j < 8; ++j) {
        const int e = t + 256 * j;
        double sacc = 0.0;
        unsigned int c = 0u;
#pragma unroll
        for (int s = 0; s < SLICES; ++s) {
            sacc += (double)es2[(size_t)s * MEXP + e];
            c    += cnt2[(size_t)s * MEXP + e];
        }
        avg[j] = sacc / (double)NROWS;
        cnt[j] = c;
        tot += avg[j];
    }
    double denom = block_reduce_d(tot, s4, lane, wid);
    denom = (denom > 1e-8) ? denom : 1e-8;

    double entl = 0.0;
#pragma unroll
    for (int j = 0; j < 8; ++j) {
        double p = avg[j] / denom;
        p = (p > 1e-8) ? p : 1e-8;
        entl -= p * log(p);
    }
    const double entropy = block_reduce_d(entl, s4, lane, wid) / log(2048.0);

    double lowl = 0.0, deadl = 0.0;
    const float expected = (float)KTOP / (float)MEXP * (float)NROWS; // 32
#pragma unroll
    for (int j = 0; j < 8; ++j) {
        const float c = (float)cnt[j];
        if (c <= 0.1f * expected)  lowl  += 1.0;
        if (c <= 0.01f * expected) deadl += 1.0;
    }
    const double low  = block_reduce_d(lowl, s4, lane, wid);
    const double dead = block_reduce_d(deadl, s4, lane, wid);

    // scalar partial sums (all plain loads; tiny). cap_part has 512 entries.
    double capl = (double)cap_part[t] + (double)cap_part[t + 256];
    const double capsum = block_reduce_d(capl, s4, lane, wid);

    double lrl = 0.0, lhl = 0.0;
    for (int i = t; i < NROWS; i += 256) {
        const float2 v = lrlh[i];
        lrl += (double)v.x;
        lhl += (double)v.y;
    }
    const double lrsum = block_reduce_d(lrl, s4, lane, wid);
    const double lhsum = block_reduce_d(lhl, s4, lane, wid);

    if (t == 0) {
        const double captured = capsum / (double)NROWS;
        const double uncap    = lrsum  / (double)NROWS;
        const double recon    = lhsum  / (double)NROWS;
        out[OUT_SCAL + 0] = (float)captured;
        out[OUT_SCAL + 1] = (float)recon;
        out[OUT_SCAL + 2] = (float)uncap;
        out[OUT_SCAL + 3] = (float)entropy;
        out[OUT_SCAL + 4] = (float)(uncap + 0.01 * (1.0 - entropy));
        out[OUT_SCAL + 5] = (float)low;
        out[OUT_SCAL + 6] = (float)dead;
    }
}

// ---------------------------------------------------------------------------
extern "C" void kernel_launch(void* const* d_in, const int* in_sizes, int n_in,
                              void* d_out, int out_size, void* d_ws, size_t ws_size,
                              hipStream_t stream)
{
    const float* x = (const float*)d_in[0];
    const float* h = (const float*)d_in[1];
    const float* V = (const float*)d_in[2];
    float* out = (float*)d_out;
    char*  ws  = (char*)d_ws;

    float4*       Vt         = (float4*)(ws + WS_VT_OFF);
    float*        esum_part  = (float*)(ws + WS_ESP_OFF);
    unsigned int* cnt_part   = (unsigned int*)(ws + WS_CNTP_OFF);
    float*        cap_part   = (float*)(ws + WS_CAP_OFF);
    float2*       lrlh       = (float2*)(ws + WS_LRLH_OFF);
    float*        es2        = (float*)(ws + WS_ES2_OFF);
    unsigned int* cnt2       = (unsigned int*)(ws + WS_CNT2_OFF);

    // no memset needed: every partial slot is fully written each call

    transpose_v_kernel<<<dim3(64, 16), 256, 0, stream>>>((const float4*)V, Vt);
    energy_topk_kernel<<<EBLK, 1024, 0, stream>>>(h, out, esum_part, cnt_part,
                                                  cap_part);
    recon_kernel<<<NROWS, 256, 0, stream>>>(x, out, Vt, lrlh);
    reduce_expert_kernel<<<dim3(8, SLICES), 256, 0, stream>>>(esum_part, cnt_part,
                                                              es2, cnt2);
    finalize_kernel<<<1, 256, 0, stream>>>(es2, cnt2, cap_part, lrlh, out);
}